// Round 1
// baseline (293.827 us; speedup 1.0000x reference)
//
#include <hip/hip_runtime.h>

#define L_SEQ 4096

typedef unsigned short u16;
typedef __bf16 bf16_t;
typedef bf16_t bf16x8 __attribute__((ext_vector_type(8)));
typedef float f32x4 __attribute__((ext_vector_type(4)));
typedef unsigned short u16x8 __attribute__((ext_vector_type(8)));
typedef unsigned short u16x4 __attribute__((ext_vector_type(4)));

__device__ __forceinline__ u16 f2b(float f) {
  unsigned u = __float_as_uint(f);
  u += 0x7fffu + ((u >> 16) & 1u);   // RNE
  return (u16)(u >> 16);
}
__device__ __forceinline__ float b2f(u16 b) {
  return __uint_as_float(((unsigned)b) << 16);
}

// ---------------- fp32 -> bf16 convert (vectorized) ----------------
__global__ __launch_bounds__(256) void k_cvt(const float* __restrict__ in,
                                             u16* __restrict__ out, int n) {
  int stride = gridDim.x * blockDim.x * 4;
  for (int i = (blockIdx.x * blockDim.x + threadIdx.x) * 4; i < n; i += stride) {
    f32x4 v = *reinterpret_cast<const f32x4*>(in + i);
    u16x4 o;
    o[0] = f2b(v[0]); o[1] = f2b(v[1]); o[2] = f2b(v[2]); o[3] = f2b(v[3]);
    *reinterpret_cast<u16x4*>(out + i) = o;
  }
}

// ---------------- fp32 [R][C] -> bf16 [C][R] transpose ----------------
__global__ __launch_bounds__(256) void k_transpose_cvt(const float* __restrict__ in,
                                                       u16* __restrict__ out,
                                                       int R, int C) {
  __shared__ float tile[32][33];
  int bx = blockIdx.x * 32, by = blockIdx.y * 32;
  int tx = threadIdx.x, ty = threadIdx.y;  // block (32,8)
#pragma unroll
  for (int i = 0; i < 32; i += 8)
    tile[ty + i][tx] = in[(size_t)(by + ty + i) * C + (bx + tx)];
  __syncthreads();
#pragma unroll
  for (int i = 0; i < 32; i += 8)
    out[(size_t)(bx + ty + i) * R + (by + tx)] = f2b(tile[tx][ty + i]);
}

// ---------------- bf16 GEMM, m97 structure: C = A(MxK) * Bt(NxK)^T ----------------
// 128x128 tile, 4 waves (2x2), 16x16x32 bf16 MFMA, global_load_lds width-16 staging.
template <bool OUT_BF16>
__global__ __launch_bounds__(256) void k_gemm_bt(const u16* __restrict__ A,
                                                 const u16* __restrict__ Bt,
                                                 void* __restrict__ Cv,
                                                 int M, int N, int K) {
  __shared__ u16 As[128 * 32];
  __shared__ u16 Bs[128 * 32];
  const int tid = threadIdx.x;
  const int wid = tid >> 6, lane = tid & 63;
  const int m0 = blockIdx.y * 128, n0 = blockIdx.x * 128;
  const int wm = wid >> 1, wn = wid & 1;

  f32x4 acc[4][4];
  {
    f32x4 z = {0.f, 0.f, 0.f, 0.f};
#pragma unroll
    for (int i = 0; i < 4; ++i)
#pragma unroll
      for (int j = 0; j < 4; ++j) acc[i][j] = z;
  }

  for (int k0 = 0; k0 < K; k0 += 32) {
    // stage A tile (128x32) and Bt tile (128x32): 512 16B-chunks each, 2 per thread
#pragma unroll
    for (int i = 0; i < 2; ++i) {
      const int c = i * 256 + wid * 64 + lane;
      const int row = c >> 2, c16 = c & 3;
      const u16* srcA = A + (size_t)(m0 + row) * K + k0 + c16 * 8;
      const u16* srcB = Bt + (size_t)(n0 + row) * K + k0 + c16 * 8;
      u16* dstA = As + (size_t)(i * 256 + wid * 64) * 8;  // wave-uniform base
      u16* dstB = Bs + (size_t)(i * 256 + wid * 64) * 8;
      __builtin_amdgcn_global_load_lds(
          (const __attribute__((address_space(1))) void*)srcA,
          (__attribute__((address_space(3))) void*)dstA, 16, 0, 0);
      __builtin_amdgcn_global_load_lds(
          (const __attribute__((address_space(1))) void*)srcB,
          (__attribute__((address_space(3))) void*)dstB, 16, 0, 0);
    }
    __syncthreads();

    const int lk = (lane >> 4) * 8;
    bf16x8 af[4], bfr[4];
#pragma unroll
    for (int mi = 0; mi < 4; ++mi) {
      int r = wm * 64 + mi * 16 + (lane & 15);
      af[mi] = *reinterpret_cast<const bf16x8*>(&As[r * 32 + lk]);
    }
#pragma unroll
    for (int ni = 0; ni < 4; ++ni) {
      int cc = wn * 64 + ni * 16 + (lane & 15);
      bfr[ni] = *reinterpret_cast<const bf16x8*>(&Bs[cc * 32 + lk]);
    }
#pragma unroll
    for (int mi = 0; mi < 4; ++mi)
#pragma unroll
      for (int ni = 0; ni < 4; ++ni)
        acc[mi][ni] = __builtin_amdgcn_mfma_f32_16x16x32_bf16(af[mi], bfr[ni],
                                                              acc[mi][ni], 0, 0, 0);
    __syncthreads();
  }

  const int lc = lane & 15, lr = (lane >> 4) * 4;
#pragma unroll
  for (int mi = 0; mi < 4; ++mi)
#pragma unroll
    for (int ni = 0; ni < 4; ++ni) {
      int row0 = m0 + wm * 64 + mi * 16 + lr;
      int col = n0 + wn * 64 + ni * 16 + lc;
#pragma unroll
      for (int r = 0; r < 4; ++r) {
        float v = acc[mi][ni][r];
        if (OUT_BF16)
          ((u16*)Cv)[(size_t)(row0 + r) * N + col] = f2b(v);
        else
          ((float*)Cv)[(size_t)(row0 + r) * N + col] = v;
      }
    }
}

// ---------------- segment attention (VALU fp32, correctness-first) ----------------
// One block per (b, h, seg). Gathers Q(64x64), K(32x64), V(32x64) via hilbert map,
// softmax over 32 keys, writes output scattered back to ORIGINAL token order.
__global__ __launch_bounds__(256) void k_attn(const u16* __restrict__ qkv,
                                              const int* __restrict__ hmap,
                                              u16* __restrict__ att) {
  __shared__ float Qs[64][68];
  __shared__ float Ks[32][68];
  __shared__ float Vs[32][68];
  __shared__ float Ps[64][36];
  __shared__ float rsum[64];
  __shared__ int hm[64];

  const int blk = blockIdx.x;
  const int b = blk >> 10;          // / (HEADS*NSEG) = 1024
  const int h = (blk >> 6) & 15;
  const int s = blk & 63;
  const int t = threadIdx.x;

  if (t < 64) hm[t] = hmap[s * 64 + t];
  __syncthreads();

  // gather Q: 512 chunks of 8 bf16
#pragma unroll
  for (int rep = 0; rep < 2; ++rep) {
    int c = rep * 256 + t;
    int qi = c >> 3, d0 = (c & 7) * 8;
    const u16* p = qkv + (size_t)(b * L_SEQ + hm[qi]) * 3072 + h * 64 + d0;
    u16x8 u = *reinterpret_cast<const u16x8*>(p);
#pragma unroll
    for (int j = 0; j < 8; ++j) Qs[qi][d0 + j] = b2f(u[j]);
  }
  // gather K,V (dilated: every 2nd row): 256 chunks each
  {
    int kj = t >> 3, d0 = (t & 7) * 8;
    size_t row = (size_t)(b * L_SEQ + hm[2 * kj]) * 3072 + h * 64 + d0;
    u16x8 uk = *reinterpret_cast<const u16x8*>(qkv + row + 1024);
    u16x8 uv = *reinterpret_cast<const u16x8*>(qkv + row + 2048);
#pragma unroll
    for (int j = 0; j < 8; ++j) {
      Ks[kj][d0 + j] = b2f(uk[j]);
      Vs[kj][d0 + j] = b2f(uv[j]);
    }
  }
  __syncthreads();

  const int tr = t >> 3, tc = t & 7;
  const int qi0 = tr * 2, kj0 = tc * 4;

  // scores: each thread 2 rows x 4 cols
  {
    float sc[2][4] = {};
    for (int d = 0; d < 64; d += 4) {
      f32x4 q0 = *reinterpret_cast<const f32x4*>(&Qs[qi0][d]);
      f32x4 q1 = *reinterpret_cast<const f32x4*>(&Qs[qi0 + 1][d]);
#pragma unroll
      for (int j = 0; j < 4; ++j) {
        f32x4 kv = *reinterpret_cast<const f32x4*>(&Ks[kj0 + j][d]);
        sc[0][j] += q0[0] * kv[0] + q0[1] * kv[1] + q0[2] * kv[2] + q0[3] * kv[3];
        sc[1][j] += q1[0] * kv[0] + q1[1] * kv[1] + q1[2] * kv[2] + q1[3] * kv[3];
      }
    }
#pragma unroll
    for (int r = 0; r < 2; ++r)
#pragma unroll
      for (int j = 0; j < 4; ++j)
        Ps[qi0 + r][kj0 + j] = sc[r][j] * 0.125f;
  }
  __syncthreads();

  // softmax: one thread per row
  if (t < 64) {
    float mx = Ps[t][0];
    for (int j = 1; j < 32; ++j) mx = fmaxf(mx, Ps[t][j]);
    float sum = 0.f;
    for (int j = 0; j < 32; ++j) {
      float e = __expf(Ps[t][j] - mx);
      Ps[t][j] = e;
      sum += e;
    }
    rsum[t] = sum;
  }
  __syncthreads();

  // PV: each thread 2 rows x 8 cols; scatter back via hm (fuses inverse perm)
  {
    const int d0 = tc * 8;
    float o[2][8] = {};
    for (int j = 0; j < 32; ++j) {
      float p0 = Ps[qi0][j], p1 = Ps[qi0 + 1][j];
      f32x4 v0 = *reinterpret_cast<const f32x4*>(&Vs[j][d0]);
      f32x4 v1 = *reinterpret_cast<const f32x4*>(&Vs[j][d0 + 4]);
#pragma unroll
      for (int cc = 0; cc < 4; ++cc) {
        o[0][cc] += p0 * v0[cc]; o[0][4 + cc] += p0 * v1[cc];
        o[1][cc] += p1 * v0[cc]; o[1][4 + cc] += p1 * v1[cc];
      }
    }
    float i0 = 1.f / rsum[qi0], i1 = 1.f / rsum[qi0 + 1];
#pragma unroll
    for (int r = 0; r < 2; ++r) {
      float inv = r ? i1 : i0;
      u16x8 ov;
#pragma unroll
      for (int cc = 0; cc < 8; ++cc) ov[cc] = f2b(o[r][cc] * inv);
      u16* dst = att + (size_t)(b * L_SEQ + hm[qi0 + r]) * 1024 + h * 64 + d0;
      *reinterpret_cast<u16x8*>(dst) = ov;
    }
  }
}

extern "C" void kernel_launch(void* const* d_in, const int* in_sizes, int n_in,
                              void* d_out, int out_size, void* d_ws, size_t ws_size,
                              hipStream_t stream) {
  const float* x = (const float*)d_in[0];
  const float* w_qkv = (const float*)d_in[1];
  const float* w_proj = (const float*)d_in[2];
  const int* hmap = (const int*)d_in[3];
  float* out = (float*)d_out;

  char* ws = (char*)d_ws;
  u16* qkvb  = (u16*)(ws);                   // 16384*3072*2 = 100663296 B
  u16* xb    = (u16*)(ws + 100663296ull);    // 16384*1024*2 = 33554432 B
  u16* wqkvT = (u16*)(ws + 134217728ull);    // 3072*1024*2  = 6291456 B
  u16* wprojT= (u16*)(ws + 140509184ull);    // 1024*1024*2  = 2097152 B -> total 142606336 B
  u16* att = xb;  // xb dead after GEMM1; stream order makes the alias safe

  k_cvt<<<2048, 256, 0, stream>>>(x, xb, 16384 * 1024);
  k_transpose_cvt<<<dim3(3072 / 32, 1024 / 32), dim3(32, 8), 0, stream>>>(w_qkv, wqkvT, 1024, 3072);
  k_transpose_cvt<<<dim3(1024 / 32, 1024 / 32), dim3(32, 8), 0, stream>>>(w_proj, wprojT, 1024, 1024);
  // qkv = x @ w_qkv   (bf16 out)
  k_gemm_bt<true><<<dim3(3072 / 128, 16384 / 128), 256, 0, stream>>>(xb, wqkvT, qkvb, 16384, 3072, 1024);
  // segment attention with hilbert gather/scatter
  k_attn<<<4096, 256, 0, stream>>>(qkvb, hmap, att);
  // out = att @ w_proj (fp32 out)
  k_gemm_bt<false><<<dim3(1024 / 128, 16384 / 128), 256, 0, stream>>>(att, wprojT, out, 16384, 1024, 1024);
}

// Round 3
// 231.802 us; speedup vs baseline: 1.2676x; 1.2676x over previous
//
#include <hip/hip_runtime.h>

#define L_SEQ 4096

typedef unsigned short u16;
typedef __bf16 bf16_t;
typedef bf16_t bf16x8 __attribute__((ext_vector_type(8)));
typedef float f32x4 __attribute__((ext_vector_type(4)));
typedef unsigned short u16x8 __attribute__((ext_vector_type(8)));
typedef unsigned short u16x4 __attribute__((ext_vector_type(4)));

__device__ __forceinline__ u16 f2b(float f) {
  unsigned u = __float_as_uint(f);
  u += 0x7fffu + ((u >> 16) & 1u);   // RNE
  return (u16)(u >> 16);
}
__device__ __forceinline__ float b2f(u16 b) {
  return __uint_as_float(((unsigned)b) << 16);
}

#define FENCE asm volatile("" ::: "memory")
#define BARRIER __builtin_amdgcn_s_barrier()
#define WAIT_LGKM0 asm volatile("s_waitcnt lgkmcnt(0)" ::: "memory")
#define WAIT_VM4 asm volatile("s_waitcnt vmcnt(4)" ::: "memory")
#define SB0 __builtin_amdgcn_sched_barrier(0)

// ---------------- fp32 -> bf16 convert (vectorized) ----------------
__global__ __launch_bounds__(256) void k_cvt(const float* __restrict__ in,
                                             u16* __restrict__ out, int n) {
  int stride = gridDim.x * blockDim.x * 4;
  for (int i = (blockIdx.x * blockDim.x + threadIdx.x) * 4; i < n; i += stride) {
    f32x4 v = *reinterpret_cast<const f32x4*>(in + i);
    u16x4 o;
    o[0] = f2b(v[0]); o[1] = f2b(v[1]); o[2] = f2b(v[2]); o[3] = f2b(v[3]);
    *reinterpret_cast<u16x4*>(out + i) = o;
  }
}

// ---------------- fp32 [R][C] -> bf16 [C][R] transpose ----------------
__global__ __launch_bounds__(256) void k_transpose_cvt(const float* __restrict__ in,
                                                       u16* __restrict__ out,
                                                       int R, int C) {
  __shared__ float tile[32][33];
  int bx = blockIdx.x * 32, by = blockIdx.y * 32;
  int tx = threadIdx.x, ty = threadIdx.y;  // block (32,8)
#pragma unroll
  for (int i = 0; i < 32; i += 8)
    tile[ty + i][tx] = in[(size_t)(by + ty + i) * C + (bx + tx)];
  __syncthreads();
#pragma unroll
  for (int i = 0; i < 32; i += 8)
    out[(size_t)(bx + ty + i) * R + (by + tx)] = f2b(tile[tx][ty + i]);
}

// ---------------- 256x256 8-phase bf16 GEMM: C = A(MxK) * Bt(NxK)^T ----------------
// 8 waves (2Mx4N); wave (wm,wn) owns output rows wm*128..+127, cols wn*64..+63.
// BK=64, 128KiB LDS dbuf, st-swizzle, one 2-load stage per phase, vmcnt(4) @ P4/P8.
template <bool OUT_BF16>
__global__ __launch_bounds__(512, 2) void k_gemm256(const u16* __restrict__ A,
                                                    const u16* __restrict__ Bt,
                                                    void* __restrict__ Cv,
                                                    int M, int N, int K) {
  __shared__ __align__(16) char lds[131072];
  const int tid = threadIdx.x;
  const int wid = tid >> 6, lane = tid & 63;
  const int wm = wid >> 2, wn = wid & 3;      // 2x4 wave grid
  const int lr = lane & 15, lq = lane >> 4;
  const int xr = (lr & 7) << 4;               // read-side XOR swizzle
  const int koff0 = (lq * 16) ^ xr;           // kk=0 byte col (swizzled)
  const int koff1 = (64 | (lq * 16)) ^ xr;    // kk=1 byte col (swizzled)

  // XCD-aware block swizzle (nwg % 8 == 0 for both GEMMs here)
  const int gx = gridDim.x;
  const int flat = blockIdx.y * gx + blockIdx.x;
  const int cpx = (gx * gridDim.y) >> 3;
  const int swz = (flat & 7) * cpx + (flat >> 3);
  const int m0 = (swz / gx) * 256, n0 = (swz % gx) * 256;

  f32x4 acc[8][4];
  {
    f32x4 z = {0.f, 0.f, 0.f, 0.f};
#pragma unroll
    for (int i = 0; i < 8; ++i)
#pragma unroll
      for (int j = 0; j < 4; ++j) acc[i][j] = z;
  }
  bf16x8 a[4][2];        // A fragments for current (wm, mh) quadrant rows
  bf16x8 bb[2][2][2];    // two B fragment sets (set, ni, kk)

  // stage one 128x64 half-tile: linear LDS dest, inverse-swizzled global source
  auto stage = [&](const u16* __restrict__ src, int region, int row0, int k0) {
#pragma unroll
    for (int i = 0; i < 2; ++i) {
      const int o = i * 8192 + tid * 16;
      const int row = o >> 7;
      const int colb = (o & 127) ^ ((row & 7) << 4);
      const u16* s = src + (size_t)(row0 + row) * K + k0 + (colb >> 1);
      __builtin_amdgcn_global_load_lds(
          (const __attribute__((address_space(1))) void*)s,
          (__attribute__((address_space(3))) void*)(lds + region + i * 8192 + wid * 1024),
          16, 0, 0);
    }
  };
  // A fragment read: region = A-half `wm`, rows mh*64 + mi*16 + lr within half
  auto rdA = [&](int dbuf, int mh) {
#pragma unroll
    for (int mi = 0; mi < 4; ++mi) {
      const int base = dbuf * 65536 + wm * 16384 + (mh * 64 + mi * 16 + lr) * 128;
      a[mi][0] = *(const bf16x8*)(lds + base + koff0);
      a[mi][1] = *(const bf16x8*)(lds + base + koff1);
    }
  };
  // B fragment read: region = B-half `wn>>1`, cols (wn&1)*64 + nh*32 + ni*16 + lr
  auto rdB = [&](int dbuf, int nh, int bset) {
#pragma unroll
    for (int ni = 0; ni < 2; ++ni) {
      const int base = dbuf * 65536 + 32768 + (wn >> 1) * 16384 +
                       ((wn & 1) * 64 + nh * 32 + ni * 16 + lr) * 128;
      bb[bset][ni][0] = *(const bf16x8*)(lds + base + koff0);
      bb[bset][ni][1] = *(const bf16x8*)(lds + base + koff1);
    }
  };
  auto mfma16 = [&](int mh, int nh, int bset) {
    __builtin_amdgcn_s_setprio(1);
#pragma unroll
    for (int ni = 0; ni < 2; ++ni)
#pragma unroll
      for (int mi = 0; mi < 4; ++mi)
#pragma unroll
        for (int kk = 0; kk < 2; ++kk)
          acc[mh * 4 + mi][nh * 2 + ni] = __builtin_amdgcn_mfma_f32_16x16x32_bf16(
              a[mi][kk], bb[bset][ni][kk], acc[mh * 4 + mi][nh * 2 + ni], 0, 0, 0);
    __builtin_amdgcn_s_setprio(0);
  };

  // ---- prologue: buf0 all 4 halves @ k=0; buf1.B halves @ k=64 (12 loads) ----
  stage(A,  0,             m0,       0);    // buf0.A-h0
  stage(Bt, 32768,         n0,       0);    // buf0.B-h0
  stage(Bt, 49152,         n0 + 128, 0);    // buf0.B-h1
  stage(A,  16384,         m0 + 128, 0);    // buf0.A-h1
  stage(Bt, 65536 + 32768, n0,       64);   // buf1.B-h0
  stage(Bt, 65536 + 49152, n0 + 128, 64);   // buf1.B-h1
  WAIT_VM4; FENCE; BARRIER;                 // drains buf0's 8 loads

  const int NT = K >> 6;      // K % 128 == 0
  const int NI = NT >> 1;
  for (int it = 0; it < NI; ++it) {
    const int kP1 = (2 * it + 1) * 64;                 // always < K
    int kA = (2 * it + 2) * 64; if (kA >= K) kA = 0;   // tail: dead stage
    int kB = (2 * it + 3) * 64; if (kB >= K) kB = 0;

    // P1: (mh0,nh0) of buf0; stage buf1.A-h0 @ kP1 (old dead since prev P7)
    rdA(0, 0); rdB(0, 0, 0);
    stage(A, 65536, m0, kP1);
    FENCE; BARRIER; WAIT_LGKM0; SB0;
    mfma16(0, 0, 0);
    FENCE; BARRIER;
    // P2: (mh0,nh1); stage buf1.A-h1 @ kP1
    rdB(0, 1, 1);
    stage(A, 65536 + 16384, m0 + 128, kP1);
    FENCE; BARRIER; WAIT_LGKM0; SB0;
    mfma16(0, 1, 1);
    FENCE; BARRIER;
    // P3: (mh1,nh1); stage buf0.B-h0 @ kA (buf0.B dead after P2-trail)
    rdA(0, 1);
    stage(Bt, 32768, n0, kA);
    FENCE; BARRIER; WAIT_LGKM0; SB0;
    mfma16(1, 1, 1);
    FENCE; BARRIER;
    // P4: (mh1,nh0) regs-only; stage buf0.B-h1 @ kA; vmcnt(4) -> buf1 complete
    stage(Bt, 49152, n0 + 128, kA);
    FENCE; BARRIER; WAIT_LGKM0; SB0;
    mfma16(1, 0, 0);
    WAIT_VM4; FENCE; BARRIER;
    // P5: (mh0,nh0) of buf1; stage buf0.A-h0 @ kA (buf0.A dead after P3-trail)
    rdA(1, 0); rdB(1, 0, 0);
    stage(A, 0, m0, kA);
    FENCE; BARRIER; WAIT_LGKM0; SB0;
    mfma16(0, 0, 0);
    FENCE; BARRIER;
    // P6: (mh0,nh1); stage buf0.A-h1 @ kA
    rdB(1, 1, 1);
    stage(A, 16384, m0 + 128, kA);
    FENCE; BARRIER; WAIT_LGKM0; SB0;
    mfma16(0, 1, 1);
    FENCE; BARRIER;
    // P7: (mh1,nh1); stage buf1.B-h0 @ kB (buf1.B dead after P6-trail)
    rdA(1, 1);
    stage(Bt, 65536 + 32768, n0, kB);
    FENCE; BARRIER; WAIT_LGKM0; SB0;
    mfma16(1, 1, 1);
    FENCE; BARRIER;
    // P8: (mh1,nh0) regs-only; stage buf1.B-h1 @ kB; vmcnt(4) -> buf0 complete
    stage(Bt, 65536 + 49152, n0 + 128, kB);
    FENCE; BARRIER; WAIT_LGKM0; SB0;
    mfma16(1, 0, 0);
    WAIT_VM4; FENCE; BARRIER;
  }

  // ---- epilogue: C/D layout col=lane&15, row=(lane>>4)*4+r ----
#pragma unroll
  for (int mi = 0; mi < 8; ++mi)
#pragma unroll
    for (int ni = 0; ni < 4; ++ni) {
      const int r0 = m0 + wm * 128 + (mi >> 2) * 64 + (mi & 3) * 16 + lq * 4;
      const int c = n0 + wn * 64 + (ni >> 1) * 32 + (ni & 1) * 16 + lr;
#pragma unroll
      for (int r = 0; r < 4; ++r) {
        const float v = acc[mi][ni][r];
        if (OUT_BF16)
          ((u16*)Cv)[(size_t)(r0 + r) * N + c] = f2b(v);
        else
          ((float*)Cv)[(size_t)(r0 + r) * N + c] = v;
      }
    }
}

// ---------------- segment attention (VALU fp32) ----------------
__global__ __launch_bounds__(256) void k_attn(const u16* __restrict__ qkv,
                                              const int* __restrict__ hmap,
                                              u16* __restrict__ att) {
  __shared__ float Qs[64][68];
  __shared__ float Ks[32][68];
  __shared__ float Vs[32][68];
  __shared__ float Ps[64][36];
  __shared__ float rsum[64];
  __shared__ int hm[64];

  const int blk = blockIdx.x;
  const int b = blk >> 10;
  const int h = (blk >> 6) & 15;
  const int s = blk & 63;
  const int t = threadIdx.x;

  if (t < 64) hm[t] = hmap[s * 64 + t];
  __syncthreads();

#pragma unroll
  for (int rep = 0; rep < 2; ++rep) {
    int c = rep * 256 + t;
    int qi = c >> 3, d0 = (c & 7) * 8;
    const u16* p = qkv + (size_t)(b * L_SEQ + hm[qi]) * 3072 + h * 64 + d0;
    u16x8 u = *reinterpret_cast<const u16x8*>(p);
#pragma unroll
    for (int j = 0; j < 8; ++j) Qs[qi][d0 + j] = b2f(u[j]);
  }
  {
    int kj = t >> 3, d0 = (t & 7) * 8;
    size_t row = (size_t)(b * L_SEQ + hm[2 * kj]) * 3072 + h * 64 + d0;
    u16x8 uk = *reinterpret_cast<const u16x8*>(qkv + row + 1024);
    u16x8 uv = *reinterpret_cast<const u16x8*>(qkv + row + 2048);
#pragma unroll
    for (int j = 0; j < 8; ++j) {
      Ks[kj][d0 + j] = b2f(uk[j]);
      Vs[kj][d0 + j] = b2f(uv[j]);
    }
  }
  __syncthreads();

  const int tr = t >> 3, tc = t & 7;
  const int qi0 = tr * 2, kj0 = tc * 4;

  {
    float sc[2][4] = {};
    for (int d = 0; d < 64; d += 4) {
      f32x4 q0 = *reinterpret_cast<const f32x4*>(&Qs[qi0][d]);
      f32x4 q1 = *reinterpret_cast<const f32x4*>(&Qs[qi0 + 1][d]);
#pragma unroll
      for (int j = 0; j < 4; ++j) {
        f32x4 kv = *reinterpret_cast<const f32x4*>(&Ks[kj0 + j][d]);
        sc[0][j] += q0[0] * kv[0] + q0[1] * kv[1] + q0[2] * kv[2] + q0[3] * kv[3];
        sc[1][j] += q1[0] * kv[0] + q1[1] * kv[1] + q1[2] * kv[2] + q1[3] * kv[3];
      }
    }
#pragma unroll
    for (int r = 0; r < 2; ++r)
#pragma unroll
      for (int j = 0; j < 4; ++j)
        Ps[qi0 + r][kj0 + j] = sc[r][j] * 0.125f;
  }
  __syncthreads();

  if (t < 64) {
    float mx = Ps[t][0];
    for (int j = 1; j < 32; ++j) mx = fmaxf(mx, Ps[t][j]);
    float sum = 0.f;
    for (int j = 0; j < 32; ++j) {
      float e = __expf(Ps[t][j] - mx);
      Ps[t][j] = e;
      sum += e;
    }
    rsum[t] = sum;
  }
  __syncthreads();

  {
    const int d0 = tc * 8;
    float o[2][8] = {};
    for (int j = 0; j < 32; ++j) {
      float p0 = Ps[qi0][j], p1 = Ps[qi0 + 1][j];
      f32x4 v0 = *reinterpret_cast<const f32x4*>(&Vs[j][d0]);
      f32x4 v1 = *reinterpret_cast<const f32x4*>(&Vs[j][d0 + 4]);
#pragma unroll
      for (int cc = 0; cc < 4; ++cc) {
        o[0][cc] += p0 * v0[cc]; o[0][4 + cc] += p0 * v1[cc];
        o[1][cc] += p1 * v0[cc]; o[1][4 + cc] += p1 * v1[cc];
      }
    }
    float i0 = 1.f / rsum[qi0], i1 = 1.f / rsum[qi0 + 1];
#pragma unroll
    for (int r = 0; r < 2; ++r) {
      float inv = r ? i1 : i0;
      u16x8 ov;
#pragma unroll
      for (int cc = 0; cc < 8; ++cc) ov[cc] = f2b(o[r][cc] * inv);
      u16* dst = att + (size_t)(b * L_SEQ + hm[qi0 + r]) * 1024 + h * 64 + d0;
      *reinterpret_cast<u16x8*>(dst) = ov;
    }
  }
}

extern "C" void kernel_launch(void* const* d_in, const int* in_sizes, int n_in,
                              void* d_out, int out_size, void* d_ws, size_t ws_size,
                              hipStream_t stream) {
  const float* x = (const float*)d_in[0];
  const float* w_qkv = (const float*)d_in[1];
  const float* w_proj = (const float*)d_in[2];
  const int* hmap = (const int*)d_in[3];
  float* out = (float*)d_out;

  char* ws = (char*)d_ws;
  u16* qkvb  = (u16*)(ws);                   // 16384*3072*2 = 100663296 B
  u16* xb    = (u16*)(ws + 100663296ull);    // 16384*1024*2 = 33554432 B
  u16* wqkvT = (u16*)(ws + 134217728ull);    // 3072*1024*2  = 6291456 B
  u16* wprojT= (u16*)(ws + 140509184ull);    // 1024*1024*2  = 2097152 B -> total 142606336 B
  u16* att = xb;  // xb dead after GEMM1

  k_cvt<<<2048, 256, 0, stream>>>(x, xb, 16384 * 1024);
  k_transpose_cvt<<<dim3(3072 / 32, 1024 / 32), dim3(32, 8), 0, stream>>>(w_qkv, wqkvT, 1024, 3072);
  k_transpose_cvt<<<dim3(1024 / 32, 1024 / 32), dim3(32, 8), 0, stream>>>(w_proj, wprojT, 1024, 1024);
  // qkv = x @ w_qkv (bf16 out): grid 12 x 64 = 768 blocks
  k_gemm256<true><<<dim3(3072 / 256, 16384 / 256), 512, 0, stream>>>(xb, wqkvT, qkvb, 16384, 3072, 1024);
  k_attn<<<4096, 256, 0, stream>>>(qkvb, hmap, att);
  // out = att @ w_proj (fp32 out): grid 4 x 64 = 256 blocks
  k_gemm256<false><<<dim3(1024 / 256, 16384 / 256), 512, 0, stream>>>(att, wprojT, out, 16384, 1024, 1024);
}

// Round 4
// 193.282 us; speedup vs baseline: 1.5202x; 1.1993x over previous
//
#include <hip/hip_runtime.h>

#define L_SEQ 4096

typedef unsigned short u16;
typedef __bf16 bf16_t;
typedef bf16_t bf16x8 __attribute__((ext_vector_type(8)));
typedef float f32x4 __attribute__((ext_vector_type(4)));
typedef unsigned short u16x8 __attribute__((ext_vector_type(8)));
typedef unsigned short u16x4 __attribute__((ext_vector_type(4)));

__device__ __forceinline__ u16 f2b(float f) {
  unsigned u = __float_as_uint(f);
  u += 0x7fffu + ((u >> 16) & 1u);   // RNE
  return (u16)(u >> 16);
}
__device__ __forceinline__ float b2f(u16 b) {
  return __uint_as_float(((unsigned)b) << 16);
}

#define FENCE asm volatile("" ::: "memory")
#define BARRIER __builtin_amdgcn_s_barrier()
#define WAIT_LGKM0 asm volatile("s_waitcnt lgkmcnt(0)" ::: "memory")
#define WAIT_VM4 asm volatile("s_waitcnt vmcnt(4)" ::: "memory")
#define SB0 __builtin_amdgcn_sched_barrier(0)
#define AS1 __attribute__((address_space(1)))
#define AS3 __attribute__((address_space(3)))

// ---------------- fp32 -> bf16 convert (vectorized) ----------------
__global__ __launch_bounds__(256) void k_cvt(const float* __restrict__ in,
                                             u16* __restrict__ out, int n) {
  int stride = gridDim.x * blockDim.x * 4;
  for (int i = (blockIdx.x * blockDim.x + threadIdx.x) * 4; i < n; i += stride) {
    f32x4 v = *reinterpret_cast<const f32x4*>(in + i);
    u16x4 o;
    o[0] = f2b(v[0]); o[1] = f2b(v[1]); o[2] = f2b(v[2]); o[3] = f2b(v[3]);
    *reinterpret_cast<u16x4*>(out + i) = o;
  }
}

// ---------------- fp32 [R][C] -> bf16 [C][R] transpose ----------------
__global__ __launch_bounds__(256) void k_transpose_cvt(const float* __restrict__ in,
                                                       u16* __restrict__ out,
                                                       int R, int C) {
  __shared__ float tile[32][33];
  int bx = blockIdx.x * 32, by = blockIdx.y * 32;
  int tx = threadIdx.x, ty = threadIdx.y;  // block (32,8)
#pragma unroll
  for (int i = 0; i < 32; i += 8)
    tile[ty + i][tx] = in[(size_t)(by + ty + i) * C + (bx + tx)];
  __syncthreads();
#pragma unroll
  for (int i = 0; i < 32; i += 8)
    out[(size_t)(bx + ty + i) * R + (by + tx)] = f2b(tile[tx][ty + i]);
}

// ---------------- persistent 256x256 8-phase bf16 GEMM ----------------
// grid = 256 blocks, each does `ntiles` output tiles. Tail "wrap" stages of
// tile t pre-stage tile t+1 (identical structure to the prologue), so the
// epilogue store-drain overlaps the next tile's P1-P3.
template <bool OUT_BF16>
__global__ __launch_bounds__(512, 2) void k_gemm256p(const u16* __restrict__ A,
                                                     const u16* __restrict__ Bt,
                                                     void* __restrict__ Cv,
                                                     int M, int N, int K,
                                                     int ntiles, int gx) {
  __shared__ __align__(16) char lds[131072];
  const int tid = threadIdx.x;
  const int wid = tid >> 6, lane = tid & 63;
  const int wm = wid >> 2, wn = wid & 3;      // 2x4 wave grid
  const int lr = lane & 15, lq = lane >> 4;
  const int xr = (lr & 7) << 4;               // read-side XOR swizzle
  const int koff0 = (lq * 16) ^ xr;
  const int koff1 = (64 | (lq * 16)) ^ xr;

  const int cpx = 32 * ntiles;                // (256*ntiles)/8
  auto tilecoord = [&](int ff, int& mm, int& nn) {
    int swz = (ff & 7) * cpx + (ff >> 3);
    mm = (swz / gx) * 256; nn = (swz % gx) * 256;
  };

  // per-thread staging constants (hoisted address math)
  const int rowT = tid >> 3;                                        // 0..63
  const int colT = (((tid * 16) & 127) ^ ((rowT & 7) << 4)) >> 1;   // u16 units
  const size_t r64K = (size_t)64 * K;
  const size_t r128K = (size_t)128 * K;

  int m0, n0;
  tilecoord(blockIdx.x, m0, n0);
  const u16* pAc = A + (size_t)(m0 + rowT) * K + colT;
  const u16* pBc = Bt + (size_t)(n0 + rowT) * K + colT;

  f32x4 acc[8][4];
  bf16x8 a[4][2];
  bf16x8 bb[2][2][2];

  auto STG = [&](const u16* bp, int region, size_t hoff, int k0) {
    const u16* s0 = bp + hoff + k0;
    __builtin_amdgcn_global_load_lds((const AS1 void*)s0,
                                     (AS3 void*)(lds + region + wid * 1024), 16, 0, 0);
    __builtin_amdgcn_global_load_lds((const AS1 void*)(s0 + r64K),
                                     (AS3 void*)(lds + region + 8192 + wid * 1024), 16, 0, 0);
  };
  auto rdA = [&](int dbuf, int mh) {
#pragma unroll
    for (int mi = 0; mi < 4; ++mi) {
      const int base = dbuf * 65536 + wm * 16384 + (mh * 64 + mi * 16 + lr) * 128;
      a[mi][0] = *(const bf16x8*)(lds + base + koff0);
      a[mi][1] = *(const bf16x8*)(lds + base + koff1);
    }
  };
  auto rdB = [&](int dbuf, int nh, int bset) {
#pragma unroll
    for (int ni = 0; ni < 2; ++ni) {
      const int base = dbuf * 65536 + 32768 + (wn >> 1) * 16384 +
                       ((wn & 1) * 64 + nh * 32 + ni * 16 + lr) * 128;
      bb[bset][ni][0] = *(const bf16x8*)(lds + base + koff0);
      bb[bset][ni][1] = *(const bf16x8*)(lds + base + koff1);
    }
  };
  auto mfma16 = [&](int mh, int nh, int bset) {
    __builtin_amdgcn_s_setprio(1);
#pragma unroll
    for (int ni = 0; ni < 2; ++ni)
#pragma unroll
      for (int mi = 0; mi < 4; ++mi)
#pragma unroll
        for (int kk = 0; kk < 2; ++kk)
          acc[mh * 4 + mi][nh * 2 + ni] = __builtin_amdgcn_mfma_f32_16x16x32_bf16(
              a[mi][kk], bb[bset][ni][kk], acc[mh * 4 + mi][nh * 2 + ni], 0, 0, 0);
    __builtin_amdgcn_s_setprio(0);
  };

  // ---- prologue: buf0 all 4 halves @ k=0; buf1.B halves @ k=64 ----
  STG(pAc, 0,             0,     0);
  STG(pBc, 32768,         0,     0);
  STG(pBc, 49152,         r128K, 0);
  STG(pAc, 16384,         r128K, 0);
  STG(pBc, 65536 + 32768, 0,     64);
  STG(pBc, 65536 + 49152, r128K, 64);
  WAIT_VM4; FENCE; BARRIER;

  const int NT = K >> 6;
  const int NI = NT >> 1;

  for (int tt = 0; tt < ntiles; ++tt) {
    const bool hasn = (tt + 1 < ntiles);
    int m0n = m0, n0n = n0;
    if (hasn) tilecoord(blockIdx.x + (tt + 1) * 256, m0n, n0n);
    const u16* pAn = hasn ? (A + (size_t)(m0n + rowT) * K + colT) : pAc;
    const u16* pBn = hasn ? (Bt + (size_t)(n0n + rowT) * K + colT) : pBc;

    {
      f32x4 z = {0.f, 0.f, 0.f, 0.f};
#pragma unroll
      for (int i = 0; i < 8; ++i)
#pragma unroll
        for (int j = 0; j < 4; ++j) acc[i][j] = z;
    }

    for (int it = 0; it < NI; ++it) {
      const int kP1 = (2 * it + 1) * 64;              // always < K
      const bool last = (it == NI - 1);
      const int kA = last ? 0 : (2 * it + 2) * 64;    // wrap -> next tile k=0
      const int kB = last ? 64 : (2 * it + 3) * 64;   // wrap -> next tile k=64
      const u16* sA = last ? pAn : pAc;
      const u16* sB = last ? pBn : pBc;

      // P1: (mh0,nh0) buf0; stage buf1.A-h0 @ kP1
      rdA(0, 0); rdB(0, 0, 0);
      STG(pAc, 65536, 0, kP1);
      FENCE; BARRIER; WAIT_LGKM0; SB0;
      mfma16(0, 0, 0);
      FENCE; BARRIER;
      // P2: (mh0,nh1); stage buf1.A-h1 @ kP1
      rdB(0, 1, 1);
      STG(pAc, 65536 + 16384, r128K, kP1);
      FENCE; BARRIER; WAIT_LGKM0; SB0;
      mfma16(0, 1, 1);
      FENCE; BARRIER;
      // P3: (mh1,nh1); stage buf0.B-h0 @ kA
      rdA(0, 1);
      STG(sB, 32768, 0, kA);
      FENCE; BARRIER; WAIT_LGKM0; SB0;
      mfma16(1, 1, 1);
      FENCE; BARRIER;
      // P4: (mh1,nh0) regs-only; stage buf0.B-h1 @ kA; vmcnt(4)
      STG(sB, 49152, r128K, kA);
      FENCE; BARRIER; WAIT_LGKM0; SB0;
      mfma16(1, 0, 0);
      WAIT_VM4; FENCE; BARRIER;
      // P5: (mh0,nh0) buf1; stage buf0.A-h0 @ kA
      rdA(1, 0); rdB(1, 0, 0);
      STG(sA, 0, 0, kA);
      FENCE; BARRIER; WAIT_LGKM0; SB0;
      mfma16(0, 0, 0);
      FENCE; BARRIER;
      // P6: (mh0,nh1); stage buf0.A-h1 @ kA
      rdB(1, 1, 1);
      STG(sA, 16384, r128K, kA);
      FENCE; BARRIER; WAIT_LGKM0; SB0;
      mfma16(0, 1, 1);
      FENCE; BARRIER;
      // P7: (mh1,nh1); stage buf1.B-h0 @ kB
      rdA(1, 1);
      STG(sB, 65536 + 32768, 0, kB);
      FENCE; BARRIER; WAIT_LGKM0; SB0;
      mfma16(1, 1, 1);
      FENCE; BARRIER;
      // P8: (mh1,nh0) regs-only; stage buf1.B-h1 @ kB; vmcnt(4)
      STG(sB, 65536 + 49152, r128K, kB);
      FENCE; BARRIER; WAIT_LGKM0; SB0;
      mfma16(1, 0, 0);
      WAIT_VM4; FENCE; BARRIER;
    }

    // ---- epilogue (current tile); stores overlap next tile's P1-P3 ----
#pragma unroll
    for (int mi = 0; mi < 8; ++mi)
#pragma unroll
      for (int ni = 0; ni < 4; ++ni) {
        const int r0 = m0 + wm * 128 + (mi >> 2) * 64 + (mi & 3) * 16 + lq * 4;
        const int c = n0 + wn * 64 + (ni >> 1) * 32 + (ni & 1) * 16 + lr;
#pragma unroll
        for (int r = 0; r < 4; ++r) {
          const float v = acc[mi][ni][r];
          if (OUT_BF16)
            ((u16*)Cv)[(size_t)(r0 + r) * N + c] = f2b(v);
          else
            ((float*)Cv)[(size_t)(r0 + r) * N + c] = v;
        }
      }

    m0 = m0n; n0 = n0n; pAc = pAn; pBc = pBn;
  }
}

// ---------------- segment attention: MFMA + in-register softmax ----------------
// One block (256 thr = 4 waves) per (b,h,seg). Wave w owns q-rows 16w..16w+15.
// Q/K fragments gathered directly from global; V staged transposed (XOR-chunk
// swizzle) in LDS; P bounced through per-wave LDS into A-frag layout.
__global__ __launch_bounds__(256) void k_attn2(const u16* __restrict__ qkv,
                                               const int* __restrict__ hmap,
                                               u16* __restrict__ att) {
  __shared__ u16 VT[64 * 40];       // V^T[d][k], stride 40 u16, XOR-chunk swizzled
  __shared__ u16 Pl[4][16 * 40];    // per-wave P[16 q][32 k], stride 40 u16

  const int blk = blockIdx.x;
  const int b = blk >> 10, h = (blk >> 6) & 15, s = blk & 63;
  const int t = threadIdx.x, w = t >> 6, lane = t & 63;
  const int lr = lane & 15, lq = lane >> 4;
  const int* hm = hmap + s * 64;
  const size_t bb = (size_t)b * L_SEQ;

  // ---- stage V^T (dilated rows; XOR-chunk swizzle kills write conflicts) ----
  {
    const int kj = t >> 3, d0 = (t & 7) * 8;
    const u16* p = qkv + (bb + hm[2 * kj]) * 3072 + 2048 + h * 64 + d0;
    u16x8 v = *(const u16x8*)p;
#pragma unroll
    for (int j = 0; j < 8; ++j) {
      const int d = d0 + j;
      const int chunk = (kj >> 3) ^ ((d >> 3) & 3);
      VT[d * 40 + chunk * 8 + (kj & 7)] = v[j];
    }
  }

  // ---- Q/K fragment gather: direct global, A/B-frag layouts ----
  const u16* qp = qkv + (bb + hm[16 * w + lr]) * 3072 + h * 64 + lq * 8;
  bf16x8 aq0 = *(const bf16x8*)(qp);
  bf16x8 aq1 = *(const bf16x8*)(qp + 32);
  bf16x8 bk[2][2];
#pragma unroll
  for (int nk = 0; nk < 2; ++nk) {
    const u16* kp = qkv + (bb + hm[2 * (nk * 16 + lr)]) * 3072 + 1024 + h * 64 + lq * 8;
    bk[nk][0] = *(const bf16x8*)(kp);
    bk[nk][1] = *(const bf16x8*)(kp + 32);
  }

  // ---- scores: S[q][kcol], kcol = lr + 16*nk ----
  f32x4 z4 = {0.f, 0.f, 0.f, 0.f};
  f32x4 s0 = __builtin_amdgcn_mfma_f32_16x16x32_bf16(aq0, bk[0][0], z4, 0, 0, 0);
  s0 = __builtin_amdgcn_mfma_f32_16x16x32_bf16(aq1, bk[0][1], s0, 0, 0, 0);
  f32x4 s1 = __builtin_amdgcn_mfma_f32_16x16x32_bf16(aq0, bk[1][0], z4, 0, 0, 0);
  s1 = __builtin_amdgcn_mfma_f32_16x16x32_bf16(aq1, bk[1][1], s1, 0, 0, 0);

  // ---- in-register softmax over 32 kcols (lr-group shuffle reduce) ----
  float inv[4];
  u16* Pw = Pl[w];
#pragma unroll
  for (int r = 0; r < 4; ++r) {
    float a0 = s0[r] * 0.125f, a1 = s1[r] * 0.125f;
    float m = fmaxf(a0, a1);
    m = fmaxf(m, __shfl_xor(m, 1));
    m = fmaxf(m, __shfl_xor(m, 2));
    m = fmaxf(m, __shfl_xor(m, 4));
    m = fmaxf(m, __shfl_xor(m, 8));
    float e0 = __expf(a0 - m), e1 = __expf(a1 - m);
    float sum = e0 + e1;
    sum += __shfl_xor(sum, 1);
    sum += __shfl_xor(sum, 2);
    sum += __shfl_xor(sum, 4);
    sum += __shfl_xor(sum, 8);
    inv[r] = 1.f / sum;
    Pw[(lq * 4 + r) * 40 + lr] = f2b(e0);
    Pw[(lq * 4 + r) * 40 + 16 + lr] = f2b(e1);
  }

  __syncthreads();   // VT visible to all waves; own P writes drained

  // ---- PV: out[q][d] = sum_k P[q][k] * VT[d][k] ----
  bf16x8 ap = *(const bf16x8*)(Pw + lr * 40 + lq * 8);
  f32x4 o[4];
#pragma unroll
  for (int nd = 0; nd < 4; ++nd) {
    const int row = nd * 16 + lr;
    const int chunk = lq ^ ((row >> 3) & 3);
    bf16x8 bv = *(const bf16x8*)(VT + row * 40 + chunk * 8);
    o[nd] = __builtin_amdgcn_mfma_f32_16x16x32_bf16(ap, bv, z4, 0, 0, 0);
  }

  // ---- scatter back to original token order (fuses inverse perm) ----
#pragma unroll
  for (int r = 0; r < 4; ++r) {
    u16* dst = att + (bb + hm[16 * w + lq * 4 + r]) * 1024 + h * 64 + lr;
#pragma unroll
    for (int nd = 0; nd < 4; ++nd)
      dst[nd * 16] = f2b(o[nd][r] * inv[r]);
  }
}

extern "C" void kernel_launch(void* const* d_in, const int* in_sizes, int n_in,
                              void* d_out, int out_size, void* d_ws, size_t ws_size,
                              hipStream_t stream) {
  const float* x = (const float*)d_in[0];
  const float* w_qkv = (const float*)d_in[1];
  const float* w_proj = (const float*)d_in[2];
  const int* hmap = (const int*)d_in[3];
  float* out = (float*)d_out;

  char* ws = (char*)d_ws;
  u16* qkvb  = (u16*)(ws);                   // 16384*3072*2 = 100663296 B
  u16* xb    = (u16*)(ws + 100663296ull);    // 16384*1024*2 = 33554432 B
  u16* wqkvT = (u16*)(ws + 134217728ull);    // 3072*1024*2  = 6291456 B
  u16* wprojT= (u16*)(ws + 140509184ull);    // 1024*1024*2  = 2097152 B -> total 142606336 B
  u16* att = xb;  // xb dead after GEMM1

  k_cvt<<<2048, 256, 0, stream>>>(x, xb, 16384 * 1024);
  k_transpose_cvt<<<dim3(3072 / 32, 1024 / 32), dim3(32, 8), 0, stream>>>(w_qkv, wqkvT, 1024, 3072);
  k_transpose_cvt<<<dim3(1024 / 32, 1024 / 32), dim3(32, 8), 0, stream>>>(w_proj, wprojT, 1024, 1024);
  // qkv = x @ w_qkv (bf16 out): 256 persistent blocks x 3 tiles (grid 12x64 tiles)
  k_gemm256p<true><<<256, 512, 0, stream>>>(xb, wqkvT, qkvb, 16384, 3072, 1024, 3, 12);
  k_attn2<<<4096, 256, 0, stream>>>(qkvb, hmap, att);
  // out = att @ w_proj (fp32 out): 256 blocks x 1 tile (grid 4x64 tiles)
  k_gemm256p<false><<<256, 512, 0, stream>>>(att, wprojT, out, 16384, 1024, 1024, 1, 4);
}